// Round 3
// baseline (900.216 us; speedup 1.0000x reference)
//
#include <hip/hip_runtime.h>

typedef unsigned short u16;
typedef u16 u16x8 __attribute__((ext_vector_type(8)));
typedef __bf16 bf16x8 __attribute__((ext_vector_type(8)));
typedef float floatx4 __attribute__((ext_vector_type(4)));

#define NB 16
#define NG 4           // batches per group
#define NC 728
#define HW 38
#define NP 1444        // 38*38
#define NPIX 16819712  // 16*728*1444
#define K2 736         // K padded to 23*32
#define P2 1536        // 1444 padded to 12*128
#define M2 768         // 728 padded to 6*128

__device__ __forceinline__ float bf2f(u16 u) {
  union { unsigned int i; float f; } v; v.i = ((unsigned int)u) << 16; return v.f;
}
__device__ __forceinline__ u16 f2bf(float f) {
  union { float f; unsigned int i; } v; v.f = f;
  unsigned int r = v.i + 0x7FFFu + ((v.i >> 16) & 1u);
  return (u16)(r >> 16);
}
// dtype-agnostic scalar load: flag=1 -> fp32, flag=0 -> bf16
__device__ __forceinline__ float ldv(const void* p, int i, int f) {
  return f ? ((const float*)p)[i] : bf2f(((const u16*)p)[i]);
}

// ---------- kernel D: detect input dtype (1 = fp32, 0 = bf16-packed) ----------
// fp32 N(0,1) words have exponent field in [64,191]; two packed bf16s alias to
// apparent exponents <=5 or >=236. Majority vote over 64 words of x_FAD.
__global__ void detect_dtype(const unsigned int* __restrict__ x, int* __restrict__ flag) {
  unsigned int v = x[threadIdx.x];
  int e = (v >> 23) & 0xFF;
  int ok = (e >= 64 && e <= 191) ? 1 : 0;
  unsigned long long b = __ballot(ok);
  if (threadIdx.x == 0) *flag = (__popcll(b) >= 48) ? 1 : 0;
}

// ---------- kernel 0: fold dw-conv + BN + gamma gates into per-channel mul/add ----------
__global__ void prep_params(const void* gF, const void* gL,
                            const void* dwfw, const void* dwfb,
                            const void* dwlw, const void* dwlb,
                            const void* fs, const void* fb,
                            const void* fm, const void* fv,
                            const void* ls, const void* lb,
                            const void* lm, const void* lv,
                            float* __restrict__ mulF, float* __restrict__ addF,
                            float* __restrict__ mulL, float* __restrict__ addL,
                            const int* __restrict__ flag) {
  int f = *flag;
  int c = blockIdx.x * 256 + threadIdx.x;
  if (c >= NC) return;
  float gf = 2.f / (1.f + __expf(-ldv(gF, 0, f))) - 1.f;   // sigmoid*2-1
  float gl = 2.f / (1.f + __expf(-ldv(gL, 0, f))) - 1.f;
  float invf = ldv(fs, c, f) * rsqrtf(ldv(fv, c, f) + 1e-5f);
  mulF[c] = gl * ldv(dwfw, c, f) * invf;                              // multiplies x_LFS*att
  addF[c] = (ldv(dwfb, c, f) - ldv(fm, c, f)) * invf + ldv(fb, c, f);
  float invl = ldv(ls, c, f) * rsqrtf(ldv(lv, c, f) + 1e-5f);
  mulL[c] = gf * ldv(dwlw, c, f) * invl;                              // multiplies x_FAD*att
  addL[c] = (ldv(dwlb, c, f) - ldv(lm, c, f)) * invl + ldv(lb, c, f);
}

// ---------- kernel 1: x [b][c][p] -> xT [b_local][p(1536)][c(736)] bf16, zero-padded ----------
__global__ __launch_bounds__(256) void transpose_pad(const void* xF, const void* xL,
                                                     u16* __restrict__ xTF,
                                                     u16* __restrict__ xTL,
                                                     int bbase, const int* __restrict__ flag) {
  __shared__ u16 tile[64][66];
  int f = *flag;
  int z = blockIdx.z;
  int bl = z & 3;                 // group-local batch
  int b = bbase + bl;             // global batch
  const void* x = (z >> 2) ? xL : xF;
  u16* xT = (z >> 2) ? xTL : xTF;
  int p0 = blockIdx.x * 64, c0 = blockIdx.y * 64;
  int t = threadIdx.x;
  int pl2 = t & 31, csub = t >> 5;
#pragma unroll
  for (int it = 0; it < 8; ++it) {
    int cl = csub * 8 + it;
    int c = c0 + cl, p = p0 + pl2 * 2;
    u16 lo = 0, hi = 0;
    if (c < NC && p < NP) {
      size_t s = (size_t)(b * NC + c) * NP + p;
      if (f) {
        float2 t2 = *(const float2*)&((const float*)x)[s];
        lo = f2bf(t2.x); hi = f2bf(t2.y);
      } else {
        unsigned int v = *(const unsigned int*)&((const u16*)x)[s];
        lo = (u16)v; hi = (u16)(v >> 16);
      }
    }
    tile[cl][pl2 * 2] = lo;
    tile[cl][pl2 * 2 + 1] = hi;
  }
  __syncthreads();
  int cl2 = t & 31, psub = t >> 5;
#pragma unroll
  for (int it = 0; it < 8; ++it) {
    int pl = psub * 8 + it;
    int c = c0 + cl2 * 2;
    if (c < K2) {
      unsigned int v = (unsigned int)tile[cl2 * 2][pl] | (((unsigned int)tile[cl2 * 2 + 1][pl]) << 16);
      *(unsigned int*)&xT[(size_t)(bl * P2 + p0 + pl) * K2 + c] = v;
    }
  }
}

// ---------- kernel 2: pad 4 weight matrices to [768][736] bf16 ----------
__global__ void pad_weights(const void* W0, const void* W1,
                            const void* W2, const void* W3,
                            u16* __restrict__ Wpad, const int* __restrict__ flag) {
  int f = *flag;
  int combo = blockIdx.y;
  const void* W = combo == 0 ? W0 : combo == 1 ? W1 : combo == 2 ? W2 : W3;
  int idx = blockIdx.x * 256 + threadIdx.x;
  if (idx >= M2 * K2) return;
  int r = idx / K2, c = idx - r * K2;
  u16 v = 0;
  if (r < NC && c < NC) {
    int s = r * NC + c;
    v = f ? f2bf(((const float*)W)[s]) : ((const u16*)W)[s];
  }
  Wpad[(size_t)combo * (M2 * K2) + idx] = v;
}

// ---------- kernel 3: conv1x1 GEMM  Out[bl][o][p] = sum_c W[o][c]*xT[bl][p][c] + bias[o] ----------
// 128x128 tile, BK=32, register->ds_write staging, 16x16x32 bf16 MFMA.
__global__ __launch_bounds__(256) void conv_gemm(const u16* __restrict__ Wpad,
                                                 const u16* __restrict__ xTF,
                                                 const u16* __restrict__ xTL,
                                                 const void* b0, const void* b1,
                                                 const void* b2, const void* b3,
                                                 u16* __restrict__ Qf, u16* __restrict__ Kf,
                                                 u16* __restrict__ Ql, u16* __restrict__ Kl,
                                                 const int* __restrict__ flag) {
  __shared__ __align__(16) u16 A_lds[128 * 32];
  __shared__ __align__(16) u16 B_lds[128 * 32];
  int f = *flag;
  int t = threadIdx.x;
  int lane = t & 63, w = t >> 6;
  int z = blockIdx.z, bl = z >> 2, combo = z & 3;   // bl = group-local batch 0..3
  int o0 = blockIdx.y * 128, p0 = blockIdx.x * 128;
  const u16* Wb = Wpad + (size_t)combo * (M2 * K2);
  const u16* Xb = ((combo < 2) ? xTF : xTL) + (size_t)bl * (P2 * K2);
  const void* bias = combo == 0 ? b0 : combo == 1 ? b1 : combo == 2 ? b2 : b3;
  u16* Out = combo == 0 ? Qf : combo == 1 ? Kf : combo == 2 ? Ql : Kl;

  // staging: thread t covers row r=(t>>2) (+64 on 2nd it), 16B chunk (t&3)
  int sr = t >> 2, sc = (t & 3) * 8;
  const u16* Ag = Wb + (size_t)(o0 + sr) * K2 + sc;
  const u16* Bg = Xb + (size_t)(p0 + sr) * K2 + sc;

  floatx4 acc[4][4] = {};
  int wm = w >> 1, wn = w & 1;
  int ln = lane & 15, qd = lane >> 4;
  const u16* Ard = A_lds + (wm * 64 + ln) * 32 + qd * 8;
  const u16* Brd = B_lds + (wn * 64 + ln) * 32 + qd * 8;

  for (int kt = 0; kt < 23; ++kt) {
    int ko = kt * 32;
    u16x8 a0 = *(const u16x8*)(Ag + ko);
    u16x8 a1 = *(const u16x8*)(Ag + ko + (size_t)64 * K2);
    u16x8 bb0 = *(const u16x8*)(Bg + ko);
    u16x8 bb1 = *(const u16x8*)(Bg + ko + (size_t)64 * K2);
    __syncthreads();  // previous iteration's LDS reads complete
    *(u16x8*)&A_lds[sr * 32 + sc] = a0;
    *(u16x8*)&A_lds[(sr + 64) * 32 + sc] = a1;
    *(u16x8*)&B_lds[sr * 32 + sc] = bb0;
    *(u16x8*)&B_lds[(sr + 64) * 32 + sc] = bb1;
    __syncthreads();  // staging visible
    bf16x8 af[4], bfv[4];
#pragma unroll
    for (int mt = 0; mt < 4; ++mt) af[mt] = *(const bf16x8*)(Ard + mt * 16 * 32);
#pragma unroll
    for (int nt = 0; nt < 4; ++nt) bfv[nt] = *(const bf16x8*)(Brd + nt * 16 * 32);
#pragma unroll
    for (int mt = 0; mt < 4; ++mt)
#pragma unroll
      for (int nt = 0; nt < 4; ++nt)
        acc[mt][nt] = __builtin_amdgcn_mfma_f32_16x16x32_bf16(af[mt], bfv[nt], acc[mt][nt], 0, 0, 0);
  }

  // epilogue: C/D layout col=lane&15 (p), row=quad*4+reg (o); add bias, store bf16
#pragma unroll
  for (int mt = 0; mt < 4; ++mt)
#pragma unroll
    for (int reg = 0; reg < 4; ++reg) {
      int o_r = o0 + wm * 64 + mt * 16 + qd * 4 + reg;
      if (o_r < NC) {
        float bv = ldv(bias, o_r, f);
#pragma unroll
        for (int nt = 0; nt < 4; ++nt) {
          int p_c = p0 + wn * 64 + nt * 16 + ln;
          if (p_c < NP) Out[(size_t)(bl * NC + o_r) * NP + p_c] = f2bf(acc[mt][nt][reg] + bv);
        }
      }
    }
}

// ---------- kernel 4: per-(bl,c) energy GEMM + softmax + fused output epilogue ----------
// One wave per (b_local,c). E[i,k] = sum_j qf[i,j]kf[k,j] + ql[i,j]kl[k,j]; K-dim padded
// layout [48 rows][96 cols]: cols 0..37 = FAD j, 48..85 = LFS j, rest zero.
__global__ __launch_bounds__(64) void attn_final(const u16* __restrict__ Qf, const u16* __restrict__ Kf,
                                                 const u16* __restrict__ Ql, const u16* __restrict__ Kl,
                                                 const void* xF, const void* xL,
                                                 const float* __restrict__ mulF, const float* __restrict__ addF,
                                                 const float* __restrict__ mulL, const float* __restrict__ addL,
                                                 void* out, int bbase, const int* __restrict__ flag) {
  __shared__ __align__(16) u16 q_lds[48 * 96];
  __shared__ __align__(16) u16 k_lds[48 * 96];
  int f = *flag;
  int bc = blockIdx.x;                 // bl*NC + c
  int bl = bc / NC, c = bc - bl * NC;
  int t = threadIdx.x;
  int base = bc * NP;                  // group-local Q/K base
  int gbase = ((bbase + bl) * NC + c) * NP;  // global x/out base
  for (int d = t; d < 48 * 96; d += 64) {
    int r = d / 96, cc = d - r * 96;
    u16 qv = 0, kv = 0;
    if (r < HW) {
      if (cc < HW) { int s = base + r * HW + cc; qv = Qf[s]; kv = Kf[s]; }
      else if (cc >= 48 && cc < 48 + HW) { int s = base + r * HW + (cc - 48); qv = Ql[s]; kv = Kl[s]; }
    }
    q_lds[d] = qv; k_lds[d] = kv;
  }
  __syncthreads();
  int ln = t & 15, qd = t >> 4;
  floatx4 acc[3][3] = {};
#pragma unroll
  for (int ks = 0; ks < 3; ++ks) {
    bf16x8 af[3], bfv[3];
#pragma unroll
    for (int mt = 0; mt < 3; ++mt) af[mt] = *(const bf16x8*)&q_lds[(mt * 16 + ln) * 96 + ks * 32 + qd * 8];
#pragma unroll
    for (int nt = 0; nt < 3; ++nt) bfv[nt] = *(const bf16x8*)&k_lds[(nt * 16 + ln) * 96 + ks * 32 + qd * 8];
#pragma unroll
    for (int mt = 0; mt < 3; ++mt)
#pragma unroll
      for (int nt = 0; nt < 3; ++nt)
        acc[mt][nt] = __builtin_amdgcn_mfma_f32_16x16x32_bf16(af[mt], bfv[nt], acc[mt][nt], 0, 0, 0);
  }
  // softmax over k (axis -1). Row i lives in lanes sharing quad: reduce width 16.
  float rinv[3][4];
#pragma unroll
  for (int mt = 0; mt < 3; ++mt)
#pragma unroll
    for (int reg = 0; reg < 4; ++reg) {
      float m = -1e30f;
#pragma unroll
      for (int nt = 0; nt < 3; ++nt)
        if (nt * 16 + ln < HW) m = fmaxf(m, acc[mt][nt][reg]);
#pragma unroll
      for (int off = 8; off > 0; off >>= 1) m = fmaxf(m, __shfl_xor(m, off, 16));
      float s = 0.f;
#pragma unroll
      for (int nt = 0; nt < 3; ++nt) {
        float v = (nt * 16 + ln < HW) ? __expf(acc[mt][nt][reg] - m) : 0.f;
        acc[mt][nt][reg] = v;
        s += v;
      }
#pragma unroll
      for (int off = 8; off > 0; off >>= 1) s += __shfl_xor(s, off, 16);
      rinv[mt][reg] = 1.f / s;
    }
  float mf = mulF[c], adf = addF[c], ml = mulL[c], adl = addL[c];
#pragma unroll
  for (int mt = 0; mt < 3; ++mt)
#pragma unroll
    for (int reg = 0; reg < 4; ++reg) {
      int i = mt * 16 + qd * 4 + reg;
      if (i < HW) {
#pragma unroll
        for (int nt = 0; nt < 3; ++nt) {
          int k = nt * 16 + ln;
          if (k < HW) {
            int idx = gbase + i * HW + k;
            float a = acc[mt][nt][reg] * rinv[mt][reg];
            float xf, xl;
            if (f) { xf = ((const float*)xF)[idx]; xl = ((const float*)xL)[idx]; }
            else   { xf = bf2f(((const u16*)xF)[idx]); xl = bf2f(((const u16*)xL)[idx]); }
            float yF = fmaf(xl * a, mf, xf + adf);   // y_FAD
            float yL = fmaf(xf * a, ml, xl + adl);   // y_LFS
            if (f) {
              ((float*)out)[idx] = yF;
              ((float*)out)[NPIX + idx] = yL;
            } else {
              ((u16*)out)[idx] = f2bf(yF);
              ((u16*)out)[NPIX + idx] = f2bf(yL);
            }
          }
        }
      }
    }
}

extern "C" void kernel_launch(void* const* d_in, const int* in_sizes, int n_in,
                              void* d_out, int out_size, void* d_ws, size_t ws_size,
                              hipStream_t stream) {
  (void)in_sizes; (void)n_in; (void)out_size; (void)ws_size;
  const void* xF   = d_in[0];
  const void* xL   = d_in[1];
  const void* Wq_f = d_in[2];
  const void* bq_f = d_in[3];
  const void* Wq_l = d_in[4];
  const void* bq_l = d_in[5];
  const void* Wk_f = d_in[6];
  const void* bk_f = d_in[7];
  const void* Wk_l = d_in[8];
  const void* bk_l = d_in[9];
  const void* gF   = d_in[10];
  const void* gL   = d_in[11];
  const void* dwfw = d_in[12];
  const void* dwfb = d_in[13];
  const void* dwlw = d_in[14];
  const void* dwlb = d_in[15];
  const void* fs   = d_in[16];
  const void* fb   = d_in[17];
  const void* fm   = d_in[18];
  const void* fv   = d_in[19];
  const void* ls   = d_in[20];
  const void* lb   = d_in[21];
  const void* lm   = d_in[22];
  const void* lv   = d_in[23];

  // Workspace (small arrays first so a hypothetical ws-size overflow only
  // clips the big staging arrays' tails; peak 56.3 MB with NG=4 grouping):
  char* ws = (char*)d_ws;
  size_t off = 0;
  int*   flag = (int*)(ws + off);   off += 16;
  float* mulF = (float*)(ws + off); off += NC * sizeof(float);   // 2912 each
  float* addF = (float*)(ws + off); off += NC * sizeof(float);
  float* mulL = (float*)(ws + off); off += NC * sizeof(float);
  float* addL = (float*)(ws + off); off += NC * sizeof(float);
  u16* Wpad = (u16*)(ws + off); off += (size_t)4 * M2 * K2 * 2;  //  4,521,984
  u16* xTF  = (u16*)(ws + off); off += (size_t)NG * P2 * K2 * 2; //  9,043,968
  u16* xTL  = (u16*)(ws + off); off += (size_t)NG * P2 * K2 * 2;
  u16* Qf   = (u16*)(ws + off); off += (size_t)NG * NC * NP * 2; //  8,409,856 each
  u16* Kf   = (u16*)(ws + off); off += (size_t)NG * NC * NP * 2;
  u16* Ql   = (u16*)(ws + off); off += (size_t)NG * NC * NP * 2;
  u16* Kl   = (u16*)(ws + off); off += (size_t)NG * NC * NP * 2;

  detect_dtype<<<dim3(1), dim3(64), 0, stream>>>((const unsigned int*)xF, flag);
  prep_params<<<dim3(3), dim3(256), 0, stream>>>(gF, gL, dwfw, dwfb, dwlw, dwlb,
                                                 fs, fb, fm, fv, ls, lb, lm, lv,
                                                 mulF, addF, mulL, addL, flag);
  pad_weights<<<dim3((M2 * K2 + 255) / 256, 4), dim3(256), 0, stream>>>(Wq_f, Wk_f, Wq_l, Wk_l, Wpad, flag);
  for (int g = 0; g < NB / NG; ++g) {
    int bbase = g * NG;
    transpose_pad<<<dim3(P2 / 64, 12, 2 * NG), dim3(256), 0, stream>>>(xF, xL, xTF, xTL, bbase, flag);
    conv_gemm<<<dim3(12, 6, 4 * NG), dim3(256), 0, stream>>>(Wpad, xTF, xTL,
                                                             bq_f, bk_f, bq_l, bk_l,
                                                             Qf, Kf, Ql, Kl, flag);
    attn_final<<<dim3(NG * NC), dim3(64), 0, stream>>>(Qf, Kf, Ql, Kl, xF, xL,
                                                       mulF, addF, mulL, addL,
                                                       d_out, bbase, flag);
  }
}

// Round 4
// 809.914 us; speedup vs baseline: 1.1115x; 1.1115x over previous
//
#include <hip/hip_runtime.h>

typedef unsigned short u16;
typedef __bf16 bf16x8 __attribute__((ext_vector_type(8)));
typedef float floatx4 __attribute__((ext_vector_type(4)));

#define NB 16
#define NG 4           // batches per group (ws budget: 56.3 MB peak)
#define NC 728
#define HW 38
#define NP 1444        // 38*38
#define NPIX 16819712  // 16*728*1444
#define K2 736         // K padded to 23*32
#define P2 1536        // 1444 padded to 12*128
#define M2 768         // 728 padded to 6*128

__device__ __forceinline__ u16 f2bf(float f) {
  union { float f; unsigned int i; } v; v.f = f;
  unsigned int r = v.i + 0x7FFFu + ((v.i >> 16) & 1u);
  return (u16)(r >> 16);
}

__device__ __forceinline__ void async16(const u16* g, u16* l) {
  __builtin_amdgcn_global_load_lds((__attribute__((address_space(1))) void*)g,
                                   (__attribute__((address_space(3))) void*)l,
                                   16, 0, 0);
}

// ---------- kernel 0: fold dw-conv + BN + gamma gates into per-channel mul/add ----------
__global__ void prep_params(const float* __restrict__ gF, const float* __restrict__ gL,
                            const float* __restrict__ dwfw, const float* __restrict__ dwfb,
                            const float* __restrict__ dwlw, const float* __restrict__ dwlb,
                            const float* __restrict__ fs, const float* __restrict__ fb,
                            const float* __restrict__ fm, const float* __restrict__ fv,
                            const float* __restrict__ ls, const float* __restrict__ lb,
                            const float* __restrict__ lm, const float* __restrict__ lv,
                            float* __restrict__ mulF, float* __restrict__ addF,
                            float* __restrict__ mulL, float* __restrict__ addL) {
  int c = blockIdx.x * 256 + threadIdx.x;
  if (c >= NC) return;
  float gf = 2.f / (1.f + __expf(-gF[0])) - 1.f;   // sigmoid*2-1
  float gl = 2.f / (1.f + __expf(-gL[0])) - 1.f;
  float invf = fs[c] * rsqrtf(fv[c] + 1e-5f);
  mulF[c] = gl * dwfw[c] * invf;                              // multiplies x_LFS*att
  addF[c] = (dwfb[c] - fm[c]) * invf + fb[c];
  float invl = ls[c] * rsqrtf(lv[c] + 1e-5f);
  mulL[c] = gf * dwlw[c] * invl;                              // multiplies x_FAD*att
  addL[c] = (dwlb[c] - lm[c]) * invl + lb[c];
}

// ---------- kernel 1: x fp32 [b][c][p] -> xT bf16 [b_local][p(1536)][c(736)] zero-padded ----------
__global__ __launch_bounds__(256) void transpose_pad(const float* __restrict__ xF,
                                                     const float* __restrict__ xL,
                                                     u16* __restrict__ xTF,
                                                     u16* __restrict__ xTL,
                                                     int bbase) {
  __shared__ u16 tile[64][68];
  int z = blockIdx.z;
  int bl = z & 3;                 // group-local batch
  int b = bbase + bl;             // global batch
  const float* x = (z >> 2) ? xL : xF;
  u16* xT = (z >> 2) ? xTL : xTF;
  int p0 = blockIdx.x * 64, c0 = blockIdx.y * 64;
  int t = threadIdx.x;
  // phase 1: float4 loads; 16 lanes cover 64 p, 16 c-rows per iter, 4 iters
  int pl4 = (t & 15) * 4, csub = t >> 4;
  bool fullp = (p0 + 63) < NP;
#pragma unroll
  for (int it = 0; it < 4; ++it) {
    int cl = it * 16 + csub;
    int c = c0 + cl, p = p0 + pl4;
    u16 o0v = 0, o1 = 0, o2 = 0, o3 = 0;
    if (c < NC) {
      const float* src = &x[(size_t)(b * NC + c) * NP + p];
      if (fullp) {
        float4 v = *(const float4*)src;
        o0v = f2bf(v.x); o1 = f2bf(v.y); o2 = f2bf(v.z); o3 = f2bf(v.w);
      } else {
        if (p + 0 < NP) o0v = f2bf(src[0]);
        if (p + 1 < NP) o1 = f2bf(src[1]);
        if (p + 2 < NP) o2 = f2bf(src[2]);
        if (p + 3 < NP) o3 = f2bf(src[3]);
      }
    }
    tile[cl][pl4] = o0v; tile[cl][pl4 + 1] = o1; tile[cl][pl4 + 2] = o2; tile[cl][pl4 + 3] = o3;
  }
  __syncthreads();
  // phase 2: write [p][c] with 2 consecutive c per thread (4B stores)
  int cl2 = t & 31, psub = t >> 5;
#pragma unroll
  for (int it = 0; it < 8; ++it) {
    int pl = psub * 8 + it;
    int c = c0 + cl2 * 2;
    if (c < K2) {
      unsigned int v = (unsigned int)tile[cl2 * 2][pl] | (((unsigned int)tile[cl2 * 2 + 1][pl]) << 16);
      *(unsigned int*)&xT[(size_t)(bl * P2 + p0 + pl) * K2 + c] = v;
    }
  }
}

// ---------- kernel 2: pad 4 weight matrices to [768][736] bf16 ----------
__global__ void pad_weights(const float* __restrict__ W0, const float* __restrict__ W1,
                            const float* __restrict__ W2, const float* __restrict__ W3,
                            u16* __restrict__ Wpad) {
  int combo = blockIdx.y;
  const float* W = combo == 0 ? W0 : combo == 1 ? W1 : combo == 2 ? W2 : W3;
  int idx = blockIdx.x * 256 + threadIdx.x;
  if (idx >= M2 * K2) return;
  int r = idx / K2, c = idx - r * K2;
  u16 v = (r < NC && c < NC) ? f2bf(W[r * NC + c]) : (u16)0;
  Wpad[(size_t)combo * (M2 * K2) + idx] = v;
}

// ---------- kernel 3: conv1x1 GEMM  Out[bl][o][p] = sum_c W[o][c]*xT[bl][p][c] + bias[o] ----------
// m97 recipe: 128x128 tile, BK=32, global_load_lds width-16 staging, 16x16x32 bf16 MFMA.
__global__ __launch_bounds__(256) void conv_gemm(const u16* __restrict__ Wpad,
                                                 const u16* __restrict__ xTF,
                                                 const u16* __restrict__ xTL,
                                                 const float* __restrict__ b0, const float* __restrict__ b1,
                                                 const float* __restrict__ b2, const float* __restrict__ b3,
                                                 u16* __restrict__ Qf, u16* __restrict__ Kf,
                                                 u16* __restrict__ Ql, u16* __restrict__ Kl) {
  __shared__ __align__(16) u16 A_lds[128 * 32];
  __shared__ __align__(16) u16 B_lds[128 * 32];
  int t = threadIdx.x;
  int lane = t & 63, w = t >> 6;
  int z = blockIdx.z, bl = z >> 2, combo = z & 3;   // bl = group-local batch 0..3
  int o0 = blockIdx.y * 128, p0 = blockIdx.x * 128;
  const u16* Wb = Wpad + (size_t)combo * (M2 * K2);
  const u16* Xb = ((combo < 2) ? xTF : xTL) + (size_t)bl * (P2 * K2);
  const float* bias = combo == 0 ? b0 : combo == 1 ? b1 : combo == 2 ? b2 : b3;
  u16* Out = combo == 0 ? Qf : combo == 1 ? Kf : combo == 2 ? Ql : Kl;

  // async staging: wave w covers 32 rows (2 calls x 16 rows); lane L -> row L/4, 16B chunk L%4
  const u16* Ag = Wb + (size_t)(o0 + w * 32 + (lane >> 2)) * K2 + (lane & 3) * 8;
  const u16* Bg = Xb + (size_t)(p0 + w * 32 + (lane >> 2)) * K2 + (lane & 3) * 8;
  u16* Al = A_lds + w * 32 * 32;   // wave-uniform LDS base (HW adds lane*16B)
  u16* Bl = B_lds + w * 32 * 32;

  floatx4 acc[4][4] = {};
  int wm = w >> 1, wn = w & 1;
  int ln = lane & 15, qd = lane >> 4;
  const u16* Ard = A_lds + (wm * 64 + ln) * 32 + qd * 8;
  const u16* Brd = B_lds + (wn * 64 + ln) * 32 + qd * 8;

  for (int kt = 0; kt < 23; ++kt) {
    int ko = kt * 32;
    async16(Ag + ko, Al);
    async16(Ag + ko + 16 * K2, Al + 16 * 32);
    async16(Bg + ko, Bl);
    async16(Bg + ko + 16 * K2, Bl + 16 * 32);
    __syncthreads();  // compiler drains vmcnt before s_barrier -> LDS visible
    bf16x8 af[4], bfv[4];
#pragma unroll
    for (int mt = 0; mt < 4; ++mt) af[mt] = *(const bf16x8*)(Ard + mt * 16 * 32);
#pragma unroll
    for (int nt = 0; nt < 4; ++nt) bfv[nt] = *(const bf16x8*)(Brd + nt * 16 * 32);
#pragma unroll
    for (int mt = 0; mt < 4; ++mt)
#pragma unroll
      for (int nt = 0; nt < 4; ++nt)
        acc[mt][nt] = __builtin_amdgcn_mfma_f32_16x16x32_bf16(af[mt], bfv[nt], acc[mt][nt], 0, 0, 0);
    __syncthreads();  // all reads done before next staging overwrites
  }

  // epilogue: C/D layout col=lane&15 (p), row=quad*4+reg (o); add bias, store bf16
#pragma unroll
  for (int mt = 0; mt < 4; ++mt)
#pragma unroll
    for (int reg = 0; reg < 4; ++reg) {
      int o_r = o0 + wm * 64 + mt * 16 + qd * 4 + reg;
      if (o_r < NC) {
        float bv = bias[o_r];
#pragma unroll
        for (int nt = 0; nt < 4; ++nt) {
          int p_c = p0 + wn * 64 + nt * 16 + ln;
          if (p_c < NP) Out[(size_t)(bl * NC + o_r) * NP + p_c] = f2bf(acc[mt][nt][reg] + bv);
        }
      }
    }
}

// ---------- kernel 4: per-(bl,c) energy GEMM + softmax + fused output epilogue ----------
// One wave per (b_local,c). E[i,k] = sum_j qf[i,j]kf[k,j] + ql[i,j]kl[k,j]; K-dim padded
// layout [48 rows][96 cols]: cols 0..37 = FAD j, 48..85 = LFS j, rest zero.
__global__ __launch_bounds__(64) void attn_final(const u16* __restrict__ Qf, const u16* __restrict__ Kf,
                                                 const u16* __restrict__ Ql, const u16* __restrict__ Kl,
                                                 const float* __restrict__ xF, const float* __restrict__ xL,
                                                 const float* __restrict__ mulF, const float* __restrict__ addF,
                                                 const float* __restrict__ mulL, const float* __restrict__ addL,
                                                 float* __restrict__ out, int bbase) {
  __shared__ __align__(16) u16 q_lds[48 * 96];
  __shared__ __align__(16) u16 k_lds[48 * 96];
  int bc = blockIdx.x;                 // bl*NC + c
  int bl = bc / NC, c = bc - bl * NC;
  int t = threadIdx.x;
  int base = bc * NP;                  // group-local Q/K base
  int gbase = ((bbase + bl) * NC + c) * NP;  // global x/out base
  for (int d = t; d < 48 * 96; d += 64) {
    int r = d / 96, cc = d - r * 96;
    u16 qv = 0, kv = 0;
    if (r < HW) {
      if (cc < HW) { int s = base + r * HW + cc; qv = Qf[s]; kv = Kf[s]; }
      else if (cc >= 48 && cc < 48 + HW) { int s = base + r * HW + (cc - 48); qv = Ql[s]; kv = Kl[s]; }
    }
    q_lds[d] = qv; k_lds[d] = kv;
  }
  __syncthreads();
  int ln = t & 15, qd = t >> 4;
  floatx4 acc[3][3] = {};
#pragma unroll
  for (int ks = 0; ks < 3; ++ks) {
    bf16x8 af[3], bfv[3];
#pragma unroll
    for (int mt = 0; mt < 3; ++mt) af[mt] = *(const bf16x8*)&q_lds[(mt * 16 + ln) * 96 + ks * 32 + qd * 8];
#pragma unroll
    for (int nt = 0; nt < 3; ++nt) bfv[nt] = *(const bf16x8*)&k_lds[(nt * 16 + ln) * 96 + ks * 32 + qd * 8];
#pragma unroll
    for (int mt = 0; mt < 3; ++mt)
#pragma unroll
      for (int nt = 0; nt < 3; ++nt)
        acc[mt][nt] = __builtin_amdgcn_mfma_f32_16x16x32_bf16(af[mt], bfv[nt], acc[mt][nt], 0, 0, 0);
  }
  // softmax over k (axis -1). Row i lives in lanes sharing quad: reduce width 16.
  float rinv[3][4];
#pragma unroll
  for (int mt = 0; mt < 3; ++mt)
#pragma unroll
    for (int reg = 0; reg < 4; ++reg) {
      float m = -1e30f;
#pragma unroll
      for (int nt = 0; nt < 3; ++nt)
        if (nt * 16 + ln < HW) m = fmaxf(m, acc[mt][nt][reg]);
#pragma unroll
      for (int off = 8; off > 0; off >>= 1) m = fmaxf(m, __shfl_xor(m, off, 16));
      float s = 0.f;
#pragma unroll
      for (int nt = 0; nt < 3; ++nt) {
        float v = (nt * 16 + ln < HW) ? __expf(acc[mt][nt][reg] - m) : 0.f;
        acc[mt][nt][reg] = v;
        s += v;
      }
#pragma unroll
      for (int off = 8; off > 0; off >>= 1) s += __shfl_xor(s, off, 16);
      rinv[mt][reg] = 1.f / s;
    }
  float mf = mulF[c], adf = addF[c], ml = mulL[c], adl = addL[c];
#pragma unroll
  for (int mt = 0; mt < 3; ++mt)
#pragma unroll
    for (int reg = 0; reg < 4; ++reg) {
      int i = mt * 16 + qd * 4 + reg;
      if (i < HW) {
#pragma unroll
        for (int nt = 0; nt < 3; ++nt) {
          int k = nt * 16 + ln;
          if (k < HW) {
            int idx = gbase + i * HW + k;
            float a = acc[mt][nt][reg] * rinv[mt][reg];
            float xf = xF[idx], xl = xL[idx];
            out[idx] = fmaf(xl * a, mf, xf + adf);          // y_FAD
            out[NPIX + idx] = fmaf(xf * a, ml, xl + adl);   // y_LFS
          }
        }
      }
    }
}

extern "C" void kernel_launch(void* const* d_in, const int* in_sizes, int n_in,
                              void* d_out, int out_size, void* d_ws, size_t ws_size,
                              hipStream_t stream) {
  (void)in_sizes; (void)n_in; (void)out_size; (void)ws_size;
  const float* xF   = (const float*)d_in[0];
  const float* xL   = (const float*)d_in[1];
  const float* Wq_f = (const float*)d_in[2];
  const float* bq_f = (const float*)d_in[3];
  const float* Wq_l = (const float*)d_in[4];
  const float* bq_l = (const float*)d_in[5];
  const float* Wk_f = (const float*)d_in[6];
  const float* bk_f = (const float*)d_in[7];
  const float* Wk_l = (const float*)d_in[8];
  const float* bk_l = (const float*)d_in[9];
  const float* gF   = (const float*)d_in[10];
  const float* gL   = (const float*)d_in[11];
  const float* dwfw = (const float*)d_in[12];
  const float* dwfb = (const float*)d_in[13];
  const float* dwlw = (const float*)d_in[14];
  const float* dwlb = (const float*)d_in[15];
  const float* fs   = (const float*)d_in[16];
  const float* fb   = (const float*)d_in[17];
  const float* fm   = (const float*)d_in[18];
  const float* fv   = (const float*)d_in[19];
  const float* ls   = (const float*)d_in[20];
  const float* lb   = (const float*)d_in[21];
  const float* lm   = (const float*)d_in[22];
  const float* lv   = (const float*)d_in[23];

  // Workspace (small arrays first; peak 56.3 MB with NG=4 grouping):
  char* ws = (char*)d_ws;
  size_t off = 0;
  float* mulF = (float*)(ws + off); off += NC * sizeof(float);   // 2912 each
  float* addF = (float*)(ws + off); off += NC * sizeof(float);
  float* mulL = (float*)(ws + off); off += NC * sizeof(float);
  float* addL = (float*)(ws + off); off += NC * sizeof(float);
  off = (off + 15) & ~(size_t)15;
  u16* Wpad = (u16*)(ws + off); off += (size_t)4 * M2 * K2 * 2;  //  4,521,984
  u16* xTF  = (u16*)(ws + off); off += (size_t)NG * P2 * K2 * 2; //  9,043,968
  u16* xTL  = (u16*)(ws + off); off += (size_t)NG * P2 * K2 * 2;
  u16* Qf   = (u16*)(ws + off); off += (size_t)NG * NC * NP * 2; //  8,409,856 each
  u16* Kf   = (u16*)(ws + off); off += (size_t)NG * NC * NP * 2;
  u16* Ql   = (u16*)(ws + off); off += (size_t)NG * NC * NP * 2;
  u16* Kl   = (u16*)(ws + off); off += (size_t)NG * NC * NP * 2;

  prep_params<<<dim3(3), dim3(256), 0, stream>>>(gF, gL, dwfw, dwfb, dwlw, dwlb,
                                                 fs, fb, fm, fv, ls, lb, lm, lv,
                                                 mulF, addF, mulL, addL);
  pad_weights<<<dim3((M2 * K2 + 255) / 256, 4), dim3(256), 0, stream>>>(Wq_f, Wk_f, Wq_l, Wk_l, Wpad);
  for (int g = 0; g < NB / NG; ++g) {
    int bbase = g * NG;
    transpose_pad<<<dim3(P2 / 64, 12, 2 * NG), dim3(256), 0, stream>>>(xF, xL, xTF, xTL, bbase);
    conv_gemm<<<dim3(12, 6, 4 * NG), dim3(256), 0, stream>>>(Wpad, xTF, xTL,
                                                             bq_f, bk_f, bq_l, bk_l,
                                                             Qf, Kf, Ql, Kl);
    attn_final<<<dim3(NG * NC), dim3(64), 0, stream>>>(Qf, Kf, Ql, Kl, xF, xL,
                                                       mulF, addF, mulL, addL,
                                                       (float*)d_out, bbase);
  }
}